// Round 7
// baseline (6155.065 us; speedup 1.0000x reference)
//
#include <hip/hip_runtime.h>

typedef __attribute__((ext_vector_type(8))) short short8;
typedef __attribute__((ext_vector_type(4))) float floatx4;

#define T_STEPS 256
#define BATCH   64
#define IDIM    1024
#define HDIM    1024
#define KDIM    (IDIM + HDIM)
#define MB      16
#define HB      16
#define NWG     256             // 4 batch-groups x 64 h-groups
#define NTHR    512             // 8 waves; each owns an X-K-octant and an H-K-octant
#define A_STRIDE (KDIM + 8)

__device__ __forceinline__ unsigned short f2bf(float f) {
  unsigned u = __float_as_uint(f);
  u += 0x7FFFu + ((u >> 16) & 1u);
  return (unsigned short)(u >> 16);
}

__global__ void prep_weights(const float* __restrict__ Wx, const float* __restrict__ Wh,
                             const float* __restrict__ mx, const float* __restrict__ mh,
                             unsigned short* __restrict__ Wcat) {
  int idx = blockIdx.x * blockDim.x + threadIdx.x;
  const int total = 4 * HDIM * KDIM / 4;
  if (idx >= total) return;
  int k4 = idx & (KDIM / 4 - 1);
  int gh = idx >> 9;
  int k = k4 * 4;
  float4 v, m;
  if (k < IDIM) {
    v = *(const float4*)(Wx + (size_t)gh * IDIM + k);
    m = *(const float4*)(mx + (size_t)gh * IDIM + k);
  } else {
    v = *(const float4*)(Wh + (size_t)gh * HDIM + (k - IDIM));
    m = *(const float4*)(mh + (size_t)gh * HDIM + (k - IDIM));
  }
  ushort4 o;
  o.x = f2bf(v.x * m.x); o.y = f2bf(v.y * m.y);
  o.z = f2bf(v.z * m.z); o.w = f2bf(v.w * m.w);
  *(ushort4*)(Wcat + (size_t)gh * KDIM + k) = o;
}

// Htile[buf:2][bg:4][hg:64][row:16][col:16] bf16; init buf 0 from H0; zero flags
__global__ void prep_htile(const float* __restrict__ H0, unsigned short* __restrict__ Htile,
                           unsigned* __restrict__ flags) {
  int i = blockIdx.x * blockDim.x + threadIdx.x;
  if (i < BATCH * HDIM) {
    int b = i >> 10, h = i & 1023;
    int bg = b >> 4, r = b & 15, hg = h >> 4, c = h & 15;
    Htile[((bg * 64 + hg) * 256) + r * 16 + c] = f2bf(H0[i]);
  }
  if (i < 4 * 64 * 16) flags[i] = 0u;   // 256 flag lines (64 B each)
}

__global__ void __launch_bounds__(NTHR, 2)
lstm_main(const float* __restrict__ X,            // [T][B][I] f32
          const float* __restrict__ bias,          // [4][H] f32
          const float* __restrict__ C0,            // [B][H] f32
          const unsigned short* __restrict__ Wcat, // [4][H][K] bf16
          unsigned short* __restrict__ Htile,      // [2][4][64][16][16] bf16
          unsigned* __restrict__ flags,            // [4][64] x 16-dword lines
          float* __restrict__ out)                 // [T][B][H] f32
{
  __shared__ __align__(16) unsigned short Ash[MB * A_STRIDE];  // 65792 B
  __shared__ float parts[2][4][MB][HB + 1];                    // 8704 B double-buffered

  const int tid  = threadIdx.x;
  const int wg   = blockIdx.x;
  const int bg   = wg >> 6;
  const int hg   = wg & 63;
  const int b0   = bg * MB;
  const int h0   = hg * HB;

  const int w    = tid >> 6;       // wave 0..7
  const int lane = tid & 63;
  const int nl   = lane & 15;
  const int quad = lane >> 4;

  // ---- persistent B fragments: X octant k=[w*128,+128), H octant k=[1024+w*128,+128)
  short8 BfrX[4][4], BfrH[4][4];
  {
    const short8* wp = (const short8*)Wcat;
#pragma unroll
    for (int g = 0; g < 4; ++g) {
      const int rowbase = (g * HDIM + h0 + nl) * (KDIM / 8);
#pragma unroll
      for (int ks = 0; ks < 4; ++ks) {
        BfrX[g][ks] = wp[rowbase + w * 16 + ks * 4 + quad];
        BfrH[g][ks] = wp[rowbase + 128 + w * 16 + ks * 4 + quad];
      }
    }
  }

  // ---- per-thread cell state
  float c_state = 0.f;
  const int eb = tid >> 4;
  const int eh = tid & 15;
  if (tid < 256) c_state = C0[(b0 + eb) * HDIM + h0 + eh];

  // ---- bias pre-init entries for parts
  const int e0 = tid, e1 = tid + NTHR;
  const int p0 = (e0 >> 8) * (MB * (HB + 1)) + ((e0 >> 4) & 15) * (HB + 1) + (e0 & 15);
  const int p1 = (e1 >> 8) * (MB * (HB + 1)) + ((e1 >> 4) & 15) * (HB + 1) + (e1 & 15);
  const float binit0 = bias[(e0 >> 8) * HDIM + h0 + (e0 & 15)];
  const float binit1 = bias[(e1 >> 8) * HDIM + h0 + (e1 & 15)];

  // ---- H-tile consumer coords
  const int c8   = tid & 127;     // 8-elem column group 0..127
  const int mrow = tid >> 7;      // 0..3
  const int hgp  = c8 >> 1;       // producer tile
  const int cin  = (c8 & 1) * 8;  // column within tile

  unsigned* myflag  = flags + (bg * 64 + hg) * 16;
  const unsigned* lflag = flags + (bg * 64 + lane) * 16;   // lane-indexed (wave 0)

  // ---- preload X slice for t=0
  float4 Xpre[8];
  {
    const float4* xp = (const float4*)(X + (size_t)b0 * IDIM);
#pragma unroll
    for (int it = 0; it < 8; ++it) {
      int v = it * NTHR + tid;
      Xpre[it] = xp[(v >> 8) * (IDIM / 4) + (v & 255)];
    }
  }

  for (int t = 0; t < T_STEPS; ++t) {
    float* pcur = &parts[t & 1][0][0][0];

    // ===== PHASE P (off critical path): X stage, bias init, X-octant MFMA, prefetch
#pragma unroll
    for (int it = 0; it < 8; ++it) {
      int v = it * NTHR + tid;
      int m = v >> 8, c4 = v & 255;
      float4 f = Xpre[it];
      ushort4 o;
      o.x = f2bf(f.x); o.y = f2bf(f.y); o.z = f2bf(f.z); o.w = f2bf(f.w);
      *(ushort4*)&Ash[m * A_STRIDE + c4 * 4] = o;
    }
    pcur[p0] = binit0;
    pcur[p1] = binit1;
    __syncthreads();   // P2: X staged, parts inited

    {
      floatx4 accx[4];
#pragma unroll
      for (int g = 0; g < 4; ++g) accx[g] = floatx4{0.f, 0.f, 0.f, 0.f};
      const unsigned short* abase = &Ash[nl * A_STRIDE + w * 128 + quad * 8];
#pragma unroll
      for (int ks = 0; ks < 4; ++ks) {
        short8 af = *(const short8*)(abase + ks * 32);
#pragma unroll
        for (int g = 0; g < 4; ++g)
          accx[g] = __builtin_amdgcn_mfma_f32_16x16x32_bf16(af, BfrX[g][ks], accx[g], 0, 0, 0);
      }
#pragma unroll
      for (int g = 0; g < 4; ++g)
#pragma unroll
        for (int r = 0; r < 4; ++r)
          atomicAdd(&parts[t & 1][g][quad * 4 + r][nl], accx[g][r]);
    }
    // prefetch X for t+1 (completes during detect/H phases)
    {
      int tn = (t + 1 < T_STEPS) ? t + 1 : t;
      const float4* xp = (const float4*)(X + ((size_t)tn * BATCH + b0) * IDIM);
#pragma unroll
      for (int it = 0; it < 8; ++it) {
        int v = it * NTHR + tid;
        Xpre[it] = xp[(v >> 8) * (IDIM / 4) + (v & 255)];
      }
    }

    // ===== DETECT: wave 0 lanes each watch one producer flag (no RMW, 1 RT)
    if (t > 0 && tid < 64) {
      const unsigned tgt = (unsigned)t;
      for (;;) {
        unsigned v;
        asm volatile("global_load_dword %0, %1, off sc0 sc1\n\t"
                     "s_waitcnt vmcnt(0)"
                     : "=v"(v) : "v"(lflag) : "memory");
        if (v >= tgt) break;
        __builtin_amdgcn_s_sleep(1);
      }
    }
    __syncthreads();   // C

    // ===== POST-DETECT critical path
    // H tile gather: 4 coalesced dwordx4 per thread, loads+waitcnt in ONE asm
    {
      const unsigned short* tb = Htile + ((size_t)(t & 1) * 4 + bg) * (64 * 256);
      const unsigned short* pa = tb + hgp * 256 + mrow * 16 + cin;
      uint4 d0, d1, d2, d3;
      asm volatile(
        "global_load_dwordx4 %0, %4, off sc0 sc1\n\t"
        "global_load_dwordx4 %1, %5, off sc0 sc1\n\t"
        "global_load_dwordx4 %2, %6, off sc0 sc1\n\t"
        "global_load_dwordx4 %3, %7, off sc0 sc1\n\t"
        "s_waitcnt vmcnt(0)"
        : "=&v"(d0), "=&v"(d1), "=&v"(d2), "=&v"(d3)
        : "v"(pa), "v"(pa + 64), "v"(pa + 128), "v"(pa + 192)
        : "memory");
      *(uint4*)&Ash[(mrow +  0) * A_STRIDE + IDIM + c8 * 8] = d0;
      *(uint4*)&Ash[(mrow +  4) * A_STRIDE + IDIM + c8 * 8] = d1;
      *(uint4*)&Ash[(mrow +  8) * A_STRIDE + IDIM + c8 * 8] = d2;
      *(uint4*)&Ash[(mrow + 12) * A_STRIDE + IDIM + c8 * 8] = d3;
    }
    __syncthreads();   // A

    // H-octant MFMA
    {
      floatx4 acch[4];
#pragma unroll
      for (int g = 0; g < 4; ++g) acch[g] = floatx4{0.f, 0.f, 0.f, 0.f};
      const unsigned short* abase = &Ash[nl * A_STRIDE + IDIM + w * 128 + quad * 8];
#pragma unroll
      for (int ks = 0; ks < 4; ++ks) {
        short8 af = *(const short8*)(abase + ks * 32);
#pragma unroll
        for (int g = 0; g < 4; ++g)
          acch[g] = __builtin_amdgcn_mfma_f32_16x16x32_bf16(af, BfrH[g][ks], acch[g], 0, 0, 0);
      }
#pragma unroll
      for (int g = 0; g < 4; ++g)
#pragma unroll
        for (int r = 0; r < 4; ++r)
          atomicAdd(&parts[t & 1][g][quad * 4 + r][nl], acch[g][r]);
    }
    __syncthreads();   // B

    // elementwise update + fully-coalesced tiled H store (8 full 64B lines/WG)
    float hn = 0.f;
    if (tid < 256) {
      float gI = parts[t & 1][0][eb][eh];
      float gF = parts[t & 1][1][eb][eh];
      float gO = parts[t & 1][2][eb][eh];
      float gC = parts[t & 1][3][eb][eh];
      float ig = 1.f / (1.f + __expf(-gI));
      float fg = 1.f / (1.f + __expf(-gF));
      float og = 1.f / (1.f + __expf(-gO));
      float cb = 1.f - 2.f / (__expf(2.f * gC) + 1.f);
      c_state = fg * c_state + ig * cb;
      hn = og * (1.f - 2.f / (__expf(2.f * c_state) + 1.f));
      unsigned short hb = f2bf(hn);
      unsigned short* nb = Htile + ((size_t)((t + 1) & 1) * 4 + bg) * (64 * 256)
                         + hg * 256 + tid;
      asm volatile("global_store_short %0, %1, off sc0 sc1"
                   :: "v"(nb), "v"((unsigned)hb) : "memory");
    }
    asm volatile("s_waitcnt vmcnt(0)" ::: "memory");
    __syncthreads();   // D: all 8 store-lines ack'd at coherence point
    if (tid == 0) {
      unsigned fv = (unsigned)(t + 1);
      asm volatile("global_store_dword %0, %1, off sc0 sc1"
                   :: "v"(myflag), "v"(fv) : "memory");
    }
    // out store AFTER publish — off the serial path
    if (tid < 256)
      out[((size_t)t * BATCH + b0 + eb) * HDIM + h0 + eh] = hn;
  }
}

extern "C" void kernel_launch(void* const* d_in, const int* in_sizes, int n_in,
                              void* d_out, int out_size, void* d_ws, size_t ws_size,
                              hipStream_t stream) {
  const float* X    = (const float*)d_in[0];
  const float* Wx   = (const float*)d_in[1];
  const float* Wh   = (const float*)d_in[2];
  const float* bias = (const float*)d_in[3];
  const float* mx   = (const float*)d_in[4];
  const float* mh   = (const float*)d_in[5];
  const float* H0   = (const float*)d_in[6];
  const float* C0   = (const float*)d_in[7];
  float* out = (float*)d_out;

  unsigned short* Wcat  = (unsigned short*)d_ws;                       // 16 MB
  unsigned short* Htile = Wcat + (size_t)4 * HDIM * KDIM;              // 256 KB
  unsigned*       flags = (unsigned*)(Htile + 2 * 4 * 64 * 256);       // 16 KB

  {
    int tot = 4 * HDIM * KDIM / 4;
    prep_weights<<<(tot + 255) / 256, 256, 0, stream>>>(Wx, Wh, mx, mh, Wcat);
  }
  prep_htile<<<(BATCH * HDIM + 255) / 256, 256, 0, stream>>>(H0, Htile, flags);

  void* args[] = { (void*)&X, (void*)&bias, (void*)&C0, (void*)&Wcat,
                   (void*)&Htile, (void*)&flags, (void*)&out };
  hipLaunchCooperativeKernel(reinterpret_cast<void*>(lstm_main),
                             dim3(NWG), dim3(NTHR), args, 0, stream);
}